// Round 3
// baseline (632.662 us; speedup 1.0000x reference)
//
#include <hip/hip_runtime.h>

typedef unsigned short ushort_t;
typedef __attribute__((ext_vector_type(8))) __bf16 bf16x8;
typedef __attribute__((ext_vector_type(8))) ushort_t u16x8;
typedef __attribute__((ext_vector_type(4))) float f32x4;

__device__ __forceinline__ ushort_t f2bf(float f) {
  union { float f; unsigned int u; } v; v.f = f;
  unsigned int u = v.u;
  u += 0x7fffu + ((u >> 16) & 1u);   // round-to-nearest-even
  return (ushort_t)(u >> 16);
}

// ---------------- kernel 1: row softmax of energy + u[b][i] = sum_j A[i][j]*b_v[j]
__global__ __launch_bounds__(64) void softmax_k(
    const float* __restrict__ energy, const float* __restrict__ bval,
    float* __restrict__ Asm, float* __restrict__ u)
{
  const int row = blockIdx.x;             // b*256 + i
  const int l = threadIdx.x;              // 0..63
  const float* e = energy + (size_t)row * 256;
  float v0 = e[l], v1 = e[l + 64], v2 = e[l + 128], v3 = e[l + 192];
  float mx = fmaxf(fmaxf(v0, v1), fmaxf(v2, v3));
  #pragma unroll
  for (int o = 32; o > 0; o >>= 1) mx = fmaxf(mx, __shfl_xor(mx, o));
  v0 = __expf(v0 - mx); v1 = __expf(v1 - mx);
  v2 = __expf(v2 - mx); v3 = __expf(v3 - mx);
  float s = v0 + v1 + v2 + v3;
  #pragma unroll
  for (int o = 32; o > 0; o >>= 1) s += __shfl_xor(s, o);
  const float inv = 1.0f / s;
  v0 *= inv; v1 *= inv; v2 *= inv; v3 *= inv;
  float* Ao = Asm + (size_t)row * 256;
  Ao[l] = v0; Ao[l + 64] = v1; Ao[l + 128] = v2; Ao[l + 192] = v3;
  float ub = v0 * bval[l] + v1 * bval[l + 64] + v2 * bval[l + 128] + v3 * bval[l + 192];
  #pragma unroll
  for (int o = 32; o > 0; o >>= 1) ub += __shfl_xor(ub, o);
  if (l == 0) u[row] = ub;
}

// ---------------- kernel 2: generic small batched fp32 GEMM C = A @ B (64x64 tiles)
__global__ __launch_bounds__(256) void gemm_f32(
    const float* __restrict__ A, int lda, int sA,
    const float* __restrict__ B, int ldb, int sB,
    float* __restrict__ C, int ldc, int sC, int K)
{
  const int bz = blockIdx.z;
  A += (size_t)bz * sA; B += (size_t)bz * sB; C += (size_t)bz * sC;
  const int m0 = blockIdx.y * 64, n0 = blockIdx.x * 64;
  __shared__ float As[64][17];
  __shared__ float Bs[16][65];
  const int t = threadIdx.x, tx = t & 15, ty = t >> 4;
  float acc[4][4] = {};
  for (int k0 = 0; k0 < K; k0 += 16) {
    {
      const int r = t >> 2, kc = (t & 3) * 4;
      float4 av = *(const float4*)(A + (size_t)(m0 + r) * lda + k0 + kc);
      As[r][kc] = av.x; As[r][kc + 1] = av.y; As[r][kc + 2] = av.z; As[r][kc + 3] = av.w;
      const int rr = t >> 4, cc = (t & 15) * 4;
      float4 bv = *(const float4*)(B + (size_t)(k0 + rr) * ldb + n0 + cc);
      Bs[rr][cc] = bv.x; Bs[rr][cc + 1] = bv.y; Bs[rr][cc + 2] = bv.z; Bs[rr][cc + 3] = bv.w;
    }
    __syncthreads();
    #pragma unroll
    for (int kk = 0; kk < 16; ++kk) {
      float a[4], bb[4];
      #pragma unroll
      for (int i = 0; i < 4; ++i) a[i] = As[ty * 4 + i][kk];
      #pragma unroll
      for (int j = 0; j < 4; ++j) bb[j] = Bs[kk][tx * 4 + j];
      #pragma unroll
      for (int i = 0; i < 4; ++i)
        #pragma unroll
        for (int j = 0; j < 4; ++j) acc[i][j] += a[i] * bb[j];
    }
    __syncthreads();
  }
  #pragma unroll
  for (int i = 0; i < 4; ++i)
    #pragma unroll
    for (int j = 0; j < 4; ++j)
      C[(size_t)(m0 + ty * 4 + i) * ldc + n0 + tx * 4 + j] = acc[i][j];
}

// ---------------- kernel 3: c[b][o] = gamma*(W_re[o,:]·u[b,:] + b_re[o])
__global__ __launch_bounds__(256) void bias_k(
    const float* __restrict__ wre, const float* __restrict__ u,
    const float* __restrict__ bre, const float* __restrict__ gp,
    float* __restrict__ c)
{
  const int idx = blockIdx.x * 256 + threadIdx.x;  // 0..4095
  const int b = idx >> 9, o = idx & 511;
  const float* wrow = wre + (size_t)o * 256;
  const float* uu = u + b * 256;
  float s = 0.f;
  for (int j = 0; j < 256; ++j) s += wrow[j] * uu[j];
  c[idx] = gp[0] * (s + bre[o]);
}

// ---------------- kernel 4: P (fp32 row-major) -> gamma-scaled bf16 fragment-linear
// Ps flat index = (((b*16 + kt)*32 + mt)*64 + lane)*8 + j
//   lane = kg*16 + (m&15), kg = (k>>3)&3, kt = k>>5, mt = m>>4, j = k&7
__global__ __launch_bounds__(256) void pswz_k(
    const float* __restrict__ P, const float* __restrict__ gp,
    ushort_t* __restrict__ Ps)
{
  const int d = blockIdx.x * 256 + threadIdx.x;    // 0..2097151
  const int j = d & 7, lane = (d >> 3) & 63, mt = (d >> 9) & 31;
  const int kt = (d >> 14) & 15, b = d >> 18;
  const int kg = lane >> 4, mr = lane & 15;
  const int m = mt * 16 + mr, k = kt * 32 + kg * 8 + j;
  Ps[d] = f2bf(gp[0] * P[((size_t)b * 512 + m) * 512 + k]);
}

// ---------------- kernel 5: out[b] = (gamma*P[b])@x[b] + 2*x[b] + c[b]
// 128x128 tile, BK=64, 4 waves (2x2), wave tile 64x64 via 4x4 mfma_16x16x32_bf16
// 1-D grid, decode: b = bid&7 (XCD-pinned batch), y = (bid>>3)&3, n = bid>>5
// -> the 4 m-blocks sharing an x-slice are consecutive on one XCD (L2 reuse),
//    and the epilogue's x re-read should hit L2 (working set ~1.5 MB < 4 MB).
__global__ __launch_bounds__(256) void main_k(
    const ushort_t* __restrict__ Ps, const float* __restrict__ x,
    const float* __restrict__ cvec, float* __restrict__ out)
{
  __shared__ __align__(16) ushort_t Blds[2][8192];  // [buf][col*64 + k], XOR-swizzled
  __shared__ float clds[128];

  const int bid = blockIdx.x;
  const int b = bid & 7;
  const int yb = (bid >> 3) & 3;
  const int n0 = (bid >> 5) * 128;
  const int m0 = yb * 128;

  const int t = threadIdx.x, lane = t & 63;
  const int w = t >> 6, wr = w >> 1, wc = w & 1;

  if (t < 128) clds[t] = cvec[b * 512 + m0 + t];

  const float* xb = x + (size_t)b * (512 * 16384);
  const int c4 = t & 31;           // cols 4c4..4c4+3
  const int r0 = (t >> 5) * 8;     // k rows r0..r0+7 within the 64-row tile
  const int xcol = n0 + 4 * c4;

  f32x4 acc[4][4];
  #pragma unroll
  for (int i = 0; i < 4; ++i)
    #pragma unroll
    for (int j = 0; j < 4; ++j) acc[i][j] = (f32x4){0.f, 0.f, 0.f, 0.f};

  float4 stg[8];   // single live staging buffer (load kt+1 -> write kt+1 same iter)

  auto loadTile = [&](int kt) {
    #pragma unroll
    for (int i = 0; i < 8; ++i)
      stg[i] = *(const float4*)(xb + (size_t)(kt * 64 + r0 + i) * 16384 + xcol);
  };
  auto writeTile = [&](int bufI) {
    char* base = (char*)&Blds[bufI][0];
    #pragma unroll
    for (int cc = 0; cc < 4; ++cc) {
      const int col = 4 * c4 + cc;
      u16x8 tmp;
      #pragma unroll
      for (int i = 0; i < 8; ++i) {
        const float* fv = (const float*)&stg[i];
        tmp[i] = f2bf(fv[cc]);
      }
      const int swz = ((col >> 2) ^ col) & 7;
      const int off = col * 128 + ((r0 * 2) ^ (swz << 4));
      *(u16x8*)(base + off) = tmp;
    }
  };

  loadTile(0);
  writeTile(0);
  __syncthreads();

  const int mtb = yb * 8 + wr * 4;

  #pragma unroll
  for (int kt = 0; kt < 8; ++kt) {
    const int cur = kt & 1;
    if (kt < 7) loadTile(kt + 1);   // prefetch next tile (hides HBM under MFMA)

    bf16x8 af[2][4];
    #pragma unroll
    for (int kk = 0; kk < 2; ++kk)
      #pragma unroll
      for (int i = 0; i < 4; ++i) {
        const size_t off = ((size_t)((b * 16 + (kt * 2 + kk)) * 32 + (mtb + i))) * 512
                         + (size_t)lane * 8;
        af[kk][i] = *(const bf16x8*)(Ps + off);
      }

    const char* base = (const char*)&Blds[cur][0];
    #pragma unroll
    for (int kk = 0; kk < 2; ++kk) {
      #pragma unroll
      for (int j = 0; j < 4; ++j) {
        const int col = wc * 64 + j * 16 + (lane & 15);
        const int kb = kk * 64 + (lane >> 4) * 16;
        const int swz = ((col >> 2) ^ col) & 7;
        const bf16x8 bf = *(const bf16x8*)(base + col * 128 + (kb ^ (swz << 4)));
        #pragma unroll
        for (int i = 0; i < 4; ++i)
          acc[i][j] = __builtin_amdgcn_mfma_f32_16x16x32_bf16(af[kk][i], bf, acc[i][j], 0, 0, 0);
      }
    }

    if (kt < 7) writeTile(cur ^ 1);
    __syncthreads();
  }

  // epilogue: out = acc + 2*x + c   (C/D layout: col=lane&15, row=(lane>>4)*4+r)
  float* ob = out + (size_t)b * (512 * 16384);
  #pragma unroll
  for (int i = 0; i < 4; ++i) {
    #pragma unroll
    for (int r = 0; r < 4; ++r) {
      const int lm = wr * 64 + i * 16 + (lane >> 4) * 4 + r;
      const size_t gm = (size_t)(m0 + lm);
      const float cb = clds[lm];
      #pragma unroll
      for (int j = 0; j < 4; ++j) {
        const int gn = n0 + wc * 64 + j * 16 + (lane & 15);
        const size_t off = gm * 16384 + gn;
        ob[off] = fmaf(2.0f, xb[off], acc[i][j][r] + cb);
      }
    }
  }
}

extern "C" void kernel_launch(void* const* d_in, const int* in_sizes, int n_in,
                              void* d_out, int out_size, void* d_ws, size_t ws_size,
                              hipStream_t stream) {
  const float* energy  = (const float*)d_in[0];  // [8,256,256]
  const float* x       = (const float*)d_in[1];  // [8,512,128,128]
  const float* w_value = (const float*)d_in[2];  // [256,512]
  const float* b_value = (const float*)d_in[3];  // [256]
  const float* w_re    = (const float*)d_in[4];  // [512,256]
  const float* b_re    = (const float*)d_in[5];  // [512]
  const float* gamma   = (const float*)d_in[6];  // [1]
  float* out = (float*)d_out;

  char* ws = (char*)d_ws;
  float*    Asm = (float*)(ws);                  // 8*256*256 f32   (2 MB)
  float*    u   = (float*)(ws + 2097152);        // 8*256 f32       (8 KB)
  float*    T   = (float*)(ws + 2105344);        // 8*512*256 f32   (4 MB)
  float*    P   = (float*)(ws + 6299648);        // 8*512*512 f32   (8 MB)
  float*    c   = (float*)(ws + 14688256);       // 8*512 f32       (16 KB)
  ushort_t* Ps  = (ushort_t*)(ws + 14704640);    // 8*512*512 bf16  (4 MB)

  // A = softmax(energy), u = A @ b_value
  softmax_k<<<2048, 64, 0, stream>>>(energy, b_value, Asm, u);
  // T[b] = W_re @ A[b]          (512x256, K=256)
  gemm_f32<<<dim3(4, 8, 8), 256, 0, stream>>>(w_re, 256, 0,
                                              Asm, 256, 256 * 256,
                                              T, 256, 512 * 256, 256);
  // P[b] = T[b] @ W_v           (512x512, K=256)
  gemm_f32<<<dim3(8, 8, 8), 256, 0, stream>>>(T, 256, 512 * 256,
                                              w_value, 512, 0,
                                              P, 512, 512 * 512, 256);
  // c[b] = gamma*(W_re @ u[b] + b_re)
  bias_k<<<16, 256, 0, stream>>>(w_re, u, b_re, gamma, c);
  // P -> gamma-scaled bf16 fragment-linear
  pswz_k<<<8192, 256, 0, stream>>>(P, gamma, Ps);
  // out[b] = (gamma*P[b]) @ x[b] + 2*x[b] + c[b]
  main_k<<<4096, 256, 0, stream>>>(Ps, x, c, out);
}